// Round 11
// baseline (221.542 us; speedup 1.0000x reference)
//
#include <hip/hip_runtime.h>
#include <hip/hip_bf16.h>

// Problem constants (B=4, FEAT=256, H=W=48, NH=8, DK=DV=32, PE=10)
// I/O: all inputs fp32, output fp32 (verified round 7/8).
// R8/R9 lesson (recorded): in-kernel grid sync (arrival ctr + spin) for the
// BN reduction cost 190-400us regardless of poll primitive. Split bn_final
// is strictly better at this size.
#define NTOK 2304

typedef short  short8  __attribute__((ext_vector_type(8)));   // 8 bf16 MFMA frag
typedef unsigned short ushort8v __attribute__((ext_vector_type(8)));
typedef float  f32x4   __attribute__((ext_vector_type(4)));

static __device__ __forceinline__ unsigned short f2bfu(float f){
  __hip_bfloat16 h = __float2bfloat16(f);          // RNE
  union { __hip_bfloat16 h; unsigned short u; } cv; cv.h = h; return cv.u;
}

// ---- in-register P transpose helpers (no LDS round-trip) ------------------
static __device__ __forceinline__ void plane32(unsigned &a, unsigned &b){
  asm("v_permlane32_swap_b32 %0, %1" : "+v"(a), "+v"(b));
}
static __device__ __forceinline__ void plane16(unsigned &a, unsigned &b){
  asm("v_permlane16_swap_b32 %0, %1" : "+v"(a), "+v"(b));
}
// sa = scores keys 4q..4q+3, sb = keys 16+4q..16+4q+3 (query col cc) ->
// B-fragment short8 = P[keys 8q..8q+7][cc]. permlane32 (reg<->lane5) then
// permlane16 (reg<->lane4); verified vs MFMA C/D and A/B fragment maps.
static __device__ __forceinline__ short8 xpose_p(f32x4 sa, f32x4 sb){
  unsigned x0, x1, y0, y1;
  asm("v_cvt_pk_bf16_f32 %0, %1, %2" : "=v"(x0) : "v"(sa[0]), "v"(sa[1]));
  asm("v_cvt_pk_bf16_f32 %0, %1, %2" : "=v"(x1) : "v"(sa[2]), "v"(sa[3]));
  asm("v_cvt_pk_bf16_f32 %0, %1, %2" : "=v"(y0) : "v"(sb[0]), "v"(sb[1]));
  asm("v_cvt_pk_bf16_f32 %0, %1, %2" : "=v"(y1) : "v"(sb[2]), "v"(sb[3]));
  plane32(x0, y0);
  plane32(x1, y1);
  plane16(x0, y0);
  plane16(x1, y1);
  union { unsigned u[4]; short8 s; } r;
  r.u[0] = x0; r.u[1] = x1; r.u[2] = y0; r.u[3] = y1;
  return r.s;
}

// ---------------- workspace layout ----------------
// ws[0..512)   float bns: sum[256], sumsq[256]
// ws[512..528) spare
// ushort arena at ws+528 (offsets in ushorts):
//   qT   @ 0         2654208 (4*2304*288) -> AO (attn out, tokmaj 256-wide)
//   kT   @ 2654208   2654208
//   vT   @ 5308416   2359296
//   Qt   @ 7667712   2359296
//   Kt   @ 10027008  2359296  \__ pre (fp32 chanmaj) overlays Kt+V2 after attn
//   V2   @ 12386304  2359296  /
//   wqp  @ 14745600  73728   (pre-scaled by log2(e)/sqrt(dk))
//   wkp  @ 14819328  73728
//   wvb  @ 14893056  65536
//   wfcb @ 14958592  65536
//   w1b  @ 15024128  65536
//   w2b  @ 15089664  65536   (end 15155200)
// NEED = 2112 + 15155200*2 = 30,312,512 B

__global__ void trip_kernel(float* out, int n){
  int i = blockIdx.x*256 + threadIdx.x;
  if (i < n) out[i] = 1000.0f;   // sentinel: ws too small
}

// ---------------- fused setup: prep-transpose + PE + weight converts -------
__global__ __launch_bounds__(256) void setup_kernel(
    const float* __restrict__ q, const float* __restrict__ k,
    const float* __restrict__ v,
    const float* __restrict__ wq, const float* __restrict__ wk,
    const float* __restrict__ wv, const float* __restrict__ wfc,
    const float* __restrict__ w1, const float* __restrict__ w2,
    unsigned short* __restrict__ qT, unsigned short* __restrict__ kT,
    unsigned short* __restrict__ vT,
    unsigned short* __restrict__ wqp, unsigned short* __restrict__ wkp,
    unsigned short* __restrict__ wvb, unsigned short* __restrict__ wfcb,
    unsigned short* __restrict__ w1b, unsigned short* __restrict__ w2b,
    float* __restrict__ bns){
  const int bid = blockIdx.x;
  const int t = threadIdx.x;
  __shared__ __align__(16) unsigned short tile[64*72];

  if (bid < 1728){                       // ---- prep transpose ----
    if (bid == 0){ bns[t] = 0.f; bns[256+t] = 0.f; }
    const int x = bid % 36, rem = bid / 36;
    const int y = rem % 4, z = rem / 4;  // z 0..11
    const int tz = z >> 2, b = z & 3;
    const float* src = (tz==0) ? q : ((tz==1) ? k : v);
    unsigned short* dst = (tz==0) ? qT : ((tz==1) ? kT : vT);
    const int W = (tz==2) ? 256 : 288;
    const int n0 = x*64, c0 = y*64;
    const int jj = t & 7, cl = t >> 3;   // 8 n-chunks x 32 c-rows
    #pragma unroll
    for (int p=0; p<2; p++){
      int c = c0 + 32*p + cl;
      const float* s = src + (size_t)(b*256 + c)*NTOK + n0 + 8*jj;
      float4 f0 = *(const float4*)s;
      float4 f1 = *(const float4*)(s + 4);
      unsigned short* tr = tile + 32*p + cl;
      tr[(8*jj+0)*72] = f2bfu(f0.x); tr[(8*jj+1)*72] = f2bfu(f0.y);
      tr[(8*jj+2)*72] = f2bfu(f0.z); tr[(8*jj+3)*72] = f2bfu(f0.w);
      tr[(8*jj+4)*72] = f2bfu(f1.x); tr[(8*jj+5)*72] = f2bfu(f1.y);
      tr[(8*jj+6)*72] = f2bfu(f1.z); tr[(8*jj+7)*72] = f2bfu(f1.w);
    }
    __syncthreads();
    #pragma unroll
    for (int p=0; p<2; p++){
      int nl = 32*p + cl;
      ushort8v val = *(const ushort8v*)(tile + nl*72 + 8*jj);
      *(ushort8v*)(dst + (size_t)(b*2304 + n0 + nl)*W + c0 + 8*jj) = val;
    }
  } else if (bid < 1800){                // ---- pe_fill ----
    const int id2 = bid - 1728;
    const int x = id2 % 9, yy = id2 / 9;
    const int n = x*256 + t;             // 0..2303
    unsigned short* buf = (yy < 4) ? qT : kT;
    const int b = yy & 3;
    const int i = n / 48, j = n - 48*i;
    const float k2pi = 6.283185307179586f;
    const float f = k2pi / 48.000001f;
    float ey = (float)(i+1) * f;
    float ex = (float)(j+1) * f;
    unsigned short u[32];
    #pragma unroll
    for (int p=0; p<10; p++){
      float inv = exp2f(-2.6575424759098898f * (float)(p >> 1));
      float vy = ey*inv, vx = ex*inv, vo = k2pi*inv;
      u[p]    = f2bfu((p&1) ? cosf(vy) : sinf(vy));
      u[10+p] = f2bfu((p&1) ? cosf(vx) : sinf(vx));
      u[20+p] = f2bfu((p&1) ? cosf(vo) : sinf(vo));
    }
    u[30] = 0; u[31] = 0;
    unsigned short* dst = buf + (size_t)(b*2304 + n)*288 + 256;
    #pragma unroll
    for (int m=0; m<4; m++) *(ushort8v*)(dst + 8*m) = *(const ushort8v*)(u + 8*m);
  } else if (bid < 2376){                // ---- padw ----
    const int id3 = bid - 1800;
    const int x = id3 % 288, y = id3 / 288;
    const int idx = x*256 + t;           // 0..73727
    const float* src = y ? wk : wq;
    unsigned short* dst = y ? wkp : wqp;
    // wq scale = log2(e)/sqrt(32): scores feed exp2 directly (exp2(s*log2e)=e^s)
    const float scale = y ? 1.f : 0.25503486f;
    int row = idx / 288, col = idx - row*288;
    dst[idx] = (col < 286) ? f2bfu(src[row*286 + col] * scale) : (unsigned short)0;
  } else {                               // ---- convw ----
    const int id4 = bid - 2376;
    const int x = id4 % 256, y = id4 / 256;
    const int idx = x*256 + t;           // 0..65535
    const float* src = (y==0)?wv:((y==1)?wfc:((y==2)?w1:w2));
    unsigned short* dst = (y==0)?wvb:((y==1)?wfcb:((y==2)?w1b:w2b));
    dst[idx] = f2bfu(src[idx]);
  }
}

// ---------------- GEMM cores -----------------------------------------------
// 3-token-fragment core: wave computes 48 tok x 32 oc (B-fragment reuse x3)
template<int KSTEPS>
static __device__ __forceinline__ void gemm3_core(
    const unsigned short* __restrict__ a0,
    const unsigned short* __restrict__ a1,
    const unsigned short* __restrict__ a2,
    const unsigned short* __restrict__ wrow, int wstride, f32x4 acc[3][2]){
  #pragma unroll
  for (int kk=0; kk<KSTEPS; kk++){
    short8 af0 = *(const short8*)(a0 + 32*kk);
    short8 af1 = *(const short8*)(a1 + 32*kk);
    short8 af2 = *(const short8*)(a2 + 32*kk);
    #pragma unroll
    for (int to=0; to<2; to++){
      short8 bf = *(const short8*)(wrow + (size_t)(16*to)*wstride + 32*kk);
      acc[0][to] = __builtin_amdgcn_mfma_f32_16x16x32_bf16(af0, bf, acc[0][to], 0,0,0);
      acc[1][to] = __builtin_amdgcn_mfma_f32_16x16x32_bf16(af1, bf, acc[1][to], 0,0,0);
      acc[2][to] = __builtin_amdgcn_mfma_f32_16x16x32_bf16(af2, bf, acc[2][to], 0,0,0);
    }
  }
}

// epilogue: token-major bf16 (wave-private LDS transpose; 16 tok x 32 oc)
static __device__ __forceinline__ void epi_tok(
    const f32x4* acc, unsigned short* __restrict__ out_tok,
    int b, int tok, int n0, int lane, int quad, int cc,
    unsigned short* __restrict__ tlw){
  #pragma unroll
  for (int to=0; to<2; to++)
    #pragma unroll
    for (int r=0; r<4; r++)
      tlw[(4*quad + r)*40 + 16*to + cc] = f2bfu(acc[to][r]);
  const int row = lane & 15, ch = lane >> 4;
  ushort8v val = *(const ushort8v*)(tlw + row*40 + 8*ch);
  *(ushort8v*)(out_tok + (size_t)(b*2304 + tok + row)*256 + n0 + 8*ch) = val;
}

// epilogue: channel-major bf16
static __device__ __forceinline__ void epi_chan(
    const f32x4* acc, unsigned short* __restrict__ out_chan,
    int b, int tok, int n0, int quad, int cc){
  #pragma unroll
  for (int to=0; to<2; to++){
    ushort4 pk;
    pk.x = f2bfu(acc[to][0]); pk.y = f2bfu(acc[to][1]);
    pk.z = f2bfu(acc[to][2]); pk.w = f2bfu(acc[to][3]);
    *(ushort4*)(out_chan + (size_t)(b*256 + n0 + 16*to + cc)*NTOK + tok + 4*quad) = pk;
  }
}

// ---------------- fused QKV projections ------------------------------------
// grid (12, 8, 12): x -> 192 tok (48/wave, 3 fragments), y -> 32 oc,
// z: tz = z>>2 (0=Q,1=K,2=V), b=z&3. 1152 blocks, single dispatch round.
__global__ __launch_bounds__(256) void qkv_kernel(
    const unsigned short* __restrict__ qT, const unsigned short* __restrict__ kT,
    const unsigned short* __restrict__ vT,
    const unsigned short* __restrict__ wqp, const unsigned short* __restrict__ wkp,
    const unsigned short* __restrict__ wvb,
    unsigned short* __restrict__ Qt, unsigned short* __restrict__ Kt,
    unsigned short* __restrict__ V2){
  const int t = threadIdx.x;
  const int w = t >> 6, lane = t & 63;
  const int quad = lane >> 4, cc = lane & 15;
  const int t0 = blockIdx.x*192, n0 = blockIdx.y*32;
  const int tz = blockIdx.z >> 2, b = blockIdx.z & 3;
  const int tok = t0 + 48*w;
  __shared__ __align__(16) unsigned short tl[4*16*40];
  unsigned short* tlw = tl + w*640;

  f32x4 acc[3][2];
  #pragma unroll
  for (int f=0; f<3; f++){
    acc[f][0] = (f32x4){0.f,0.f,0.f,0.f};
    acc[f][1] = acc[f][0];
  }

  if (tz == 0){
    const unsigned short* a0 = qT + (size_t)(b*2304 + tok + cc)*288 + 8*quad;
    gemm3_core<9>(a0, a0 + (size_t)16*288, a0 + (size_t)32*288,
                  wqp + (size_t)(n0 + cc)*288 + 8*quad, 288, acc);
    epi_tok(acc[0], Qt, b, tok,      n0, lane, quad, cc, tlw);
    epi_tok(acc[1], Qt, b, tok + 16, n0, lane, quad, cc, tlw);
    epi_tok(acc[2], Qt, b, tok + 32, n0, lane, quad, cc, tlw);
  } else if (tz == 1){
    const unsigned short* a0 = kT + (size_t)(b*2304 + tok + cc)*288 + 8*quad;
    gemm3_core<9>(a0, a0 + (size_t)16*288, a0 + (size_t)32*288,
                  wkp + (size_t)(n0 + cc)*288 + 8*quad, 288, acc);
    epi_tok(acc[0], Kt, b, tok,      n0, lane, quad, cc, tlw);
    epi_tok(acc[1], Kt, b, tok + 16, n0, lane, quad, cc, tlw);
    epi_tok(acc[2], Kt, b, tok + 32, n0, lane, quad, cc, tlw);
  } else {
    const unsigned short* a0 = vT + (size_t)(b*2304 + tok + cc)*256 + 8*quad;
    gemm3_core<8>(a0, a0 + (size_t)16*256, a0 + (size_t)32*256,
                  wvb + (size_t)(n0 + cc)*256 + 8*quad, 256, acc);
    epi_chan(acc[0], V2, b, tok,      n0, quad, cc);
    epi_chan(acc[1], V2, b, tok + 16, n0, quad, cc);
    epi_chan(acc[2], V2, b, tok + 32, n0, quad, cc);
  }
}

// ---------------- fused FFN: fc -> ffn1(relu) -> ffn2 + resid + BN stats ---
// grid (144, 4), block 256 = 4 waves. Block owns 16 tokens x all 256 oc;
// intermediates in LDS [16][264] bf16; residual (fc out) in registers fp32.
__global__ __launch_bounds__(256) void ffn_kernel(
    const unsigned short* __restrict__ AO,
    const unsigned short* __restrict__ wfcb,
    const unsigned short* __restrict__ w1b,
    const unsigned short* __restrict__ w2b,
    const float* __restrict__ b1, const float* __restrict__ b2,
    float* __restrict__ pre_out, float* __restrict__ bns){
  const int t = threadIdx.x;
  const int w = t >> 6, lane = t & 63;
  const int quad = lane >> 4, cc = lane & 15;
  const int tok0 = blockIdx.x * 16;
  const int b = blockIdx.y;
  const int ocb = 64 * w;

  __shared__ __align__(16) unsigned short T0[16*264];   // Ofc (bf16 tokmaj)
  __shared__ __align__(16) unsigned short T1[16*264];   // h1

  // ---- GEMM1: Ofc = AO x wfc^T (K=256); acc1 kept live as fp32 residual --
  const unsigned short* arow = AO + (size_t)(b*2304 + tok0 + cc)*256 + 8*quad;
  f32x4 acc1[4];
  acc1[0] = (f32x4){0.f,0.f,0.f,0.f}; acc1[1]=acc1[0]; acc1[2]=acc1[0]; acc1[3]=acc1[0];
  #pragma unroll
  for (int kk=0; kk<8; kk++){
    short8 af = *(const short8*)(arow + 32*kk);
    #pragma unroll
    for (int of=0; of<4; of++){
      short8 bf = *(const short8*)(wfcb + (size_t)(ocb + 16*of + cc)*256 + 8*quad + 32*kk);
      acc1[of] = __builtin_amdgcn_mfma_f32_16x16x32_bf16(af, bf, acc1[of], 0,0,0);
    }
  }
  #pragma unroll
  for (int of=0; of<4; of++)
    #pragma unroll
    for (int r=0; r<4; r++)
      T0[(4*quad + r)*264 + ocb + 16*of + cc] = f2bfu(acc1[of][r]);
  __syncthreads();

  // ---- GEMM2: h1 = relu(Ofc x w1^T + b1) ---------------------------------
  f32x4 acc2[4];
  acc2[0] = (f32x4){0.f,0.f,0.f,0.f}; acc2[1]=acc2[0]; acc2[2]=acc2[0]; acc2[3]=acc2[0];
  #pragma unroll
  for (int kk=0; kk<8; kk++){
    short8 af = *(const short8*)(T0 + cc*264 + 8*quad + 32*kk);
    #pragma unroll
    for (int of=0; of<4; of++){
      short8 bf = *(const short8*)(w1b + (size_t)(ocb + 16*of + cc)*256 + 8*quad + 32*kk);
      acc2[of] = __builtin_amdgcn_mfma_f32_16x16x32_bf16(af, bf, acc2[of], 0,0,0);
    }
  }
  #pragma unroll
  for (int of=0; of<4; of++){
    float bv = b1[ocb + 16*of + cc];
    #pragma unroll
    for (int r=0; r<4; r++){
      float hv = fmaxf(acc2[of][r] + bv, 0.f);
      T1[(4*quad + r)*264 + ocb + 16*of + cc] = f2bfu(hv);
    }
  }
  __syncthreads();

  // ---- GEMM3: h2 = h1 x w2^T + b2; pre = h2 + Ofc(fp32); BN stats --------
  f32x4 acc3[4];
  acc3[0] = (f32x4){0.f,0.f,0.f,0.f}; acc3[1]=acc3[0]; acc3[2]=acc3[0]; acc3[3]=acc3[0];
  #pragma unroll
  for (int kk=0; kk<8; kk++){
    short8 af = *(const short8*)(T1 + cc*264 + 8*quad + 32*kk);
    #pragma unroll
    for (int of=0; of<4; of++){
      short8 bf = *(const short8*)(w2b + (size_t)(ocb + 16*of + cc)*256 + 8*quad + 32*kk);
      acc3[of] = __builtin_amdgcn_mfma_f32_16x16x32_bf16(af, bf, acc3[of], 0,0,0);
    }
  }
  #pragma unroll
  for (int of=0; of<4; of++){
    const int oc = ocb + 16*of + cc;
    float bv = b2[oc];
    float p0 = acc3[of][0] + bv + acc1[of][0];
    float p1 = acc3[of][1] + bv + acc1[of][1];
    float p2 = acc3[of][2] + bv + acc1[of][2];
    float p3 = acc3[of][3] + bv + acc1[of][3];
    *(float4*)(pre_out + (size_t)(b*256 + oc)*NTOK + tok0 + 4*quad) =
        make_float4(p0, p1, p2, p3);
    float s1 = (p0+p1)+(p2+p3);
    float s2 = (p0*p0+p1*p1)+(p2*p2+p3*p3);
    s1 += __shfl_xor(s1, 16, 64); s1 += __shfl_xor(s1, 32, 64);
    s2 += __shfl_xor(s2, 16, 64); s2 += __shfl_xor(s2, 32, 64);
    if (quad == 0){
      atomicAdd(&bns[oc],       s1);
      atomicAdd(&bns[256 + oc], s2);
    }
  }
}

// ---------------- attention: 48-query waves, key-split MFMA flash ----------
// grid (48,8,4) = 1536 blocks, block 256 = 4 waves. R10 analysis: at 64q the
// grid supplies only 18 waves/CU while LDS (25.6KB -> 6 blk/CU) and VGPR
// (64 -> 8 waves/SIMD) allow 24: grid-starved. 48q/block makes the grid
// exactly 6 blocks/CU (zero tail) = 24 waves/CU, +33% latency hiding for
// -25% per-wave work. Each wave: 3 q-fragments x 576-key slice (18 iters),
// distance-1 reload-after-use prefetch (R7: depth-2 regressed via VGPR).
// No-max softmax; full cross-wave LDS merge (4 regions x 1600 floats).
__global__ __launch_bounds__(256) void attn_kernel(
    const unsigned short* __restrict__ Qt, const unsigned short* __restrict__ Kt,
    const unsigned short* __restrict__ V2, unsigned short* __restrict__ AO){
  const int t = threadIdx.x;
  const int w = t >> 6, lane = t & 63;
  const int quad = lane >> 4, cc = lane & 15;
  const int h = blockIdx.y, b = blockIdx.z;
  const int q0 = blockIdx.x*48;

  const unsigned short* qb = Qt + (size_t)(b*2304 + q0 + cc)*256 + h*32 + 8*quad;
  short8 qf0 = *(const short8*)(qb);
  short8 qf1 = *(const short8*)(qb + 16*256);
  short8 qf2 = *(const short8*)(qb + 32*256);

  const unsigned short* kb = Kt + (size_t)(b*2304 + cc)*256 + h*32 + 8*quad;
  const unsigned short* vb = V2 + (size_t)(b*256 + h*32 + cc)*NTOK + 8*quad;

  // merge: 4 regions x 1600 floats (24 j-slots x 64 lanes + 48 lsum + pad)
  __shared__ __align__(16) float mg_lds[4*1600];

  f32x4 o00={0.f,0.f,0.f,0.f}, o10=o00, o01=o00, o11=o00, o02=o00, o12=o00;
  float lsum0=0.f, lsum1=0.f, lsum2=0.f;

  const int kstart = w*576;
  short8 kf0 = *(const short8*)(kb + (size_t)kstart*256);
  short8 kf1 = *(const short8*)(kb + (size_t)(kstart+16)*256);
  short8 vf0 = *(const short8*)(vb + kstart);
  short8 vf1 = *(const short8*)(vb + (size_t)16*NTOK + kstart);

  #pragma unroll 1
  for (int it = 0; it < 18; ++it){
    const int ko = kstart + it*32;
    const int rk = (it < 17) ? ko + 32 : kstart;   // next keys (wrap harmless)
    const f32x4 z = {0.f,0.f,0.f,0.f};

    // QK: 6 MFMA over 3 query fragments
    f32x4 s00 = __builtin_amdgcn_mfma_f32_16x16x32_bf16(kf0, qf0, z, 0,0,0);
    f32x4 s10 = __builtin_amdgcn_mfma_f32_16x16x32_bf16(kf1, qf0, z, 0,0,0);
    f32x4 s01 = __builtin_amdgcn_mfma_f32_16x16x32_bf16(kf0, qf1, z, 0,0,0);
    f32x4 s11 = __builtin_amdgcn_mfma_f32_16x16x32_bf16(kf1, qf1, z, 0,0,0);
    f32x4 s02 = __builtin_amdgcn_mfma_f32_16x16x32_bf16(kf0, qf2, z, 0,0,0);
    f32x4 s12 = __builtin_amdgcn_mfma_f32_16x16x32_bf16(kf1, qf2, z, 0,0,0);
    // reload K for next phase (last use above)
    kf0 = *(const short8*)(kb + (size_t)rk*256);
    kf1 = *(const short8*)(kb + (size_t)(rk+16)*256);

    // softmax numerator + per-qq chains (independent -> ILP)
    #pragma unroll
    for (int r=0; r<4; r++){
      s00[r] = __builtin_amdgcn_exp2f(s00[r]);
      s10[r] = __builtin_amdgcn_exp2f(s10[r]);
      s01[r] = __builtin_amdgcn_exp2f(s01[r]);
      s11[r] = __builtin_amdgcn_exp2f(s11[r]);
      s02[r] = __builtin_amdgcn_exp2f(s02[r]);
      s12[r] = __builtin_amdgcn_exp2f(s12[r]);
    }
    lsum0 += ((s00[0]+s00[1])+(s00[2]+s00[3])) + ((s10[0]+s10[1])+(s10[2]+s10[3]));
    lsum1 += ((s01[0]+s01[1])+(s01[2]+s01[3])) + ((s11[0]+s11[1])+(s11[2]+s11[3]));
    lsum2 += ((s02[0]+s02[1])+(s02[2]+s02[3])) + ((s12[0]+s12[1])+(s12[2]+s12[3]));

    short8 pf0 = xpose_p(s00, s10);
    short8 pf1 = xpose_p(s01, s11);
    short8 pf2 = xpose_p(s02, s12);

    o00 = __builtin_amdgcn_mfma_f32_16x16x32_bf16(vf0, pf0, o00, 0,0,0);
    o10 = __builtin_amdgcn_mfma_f32_16x16x32_bf16(vf1, pf0, o10, 0,0,0);
    o01 = __builtin_amdgcn_mfma_f32_16x16x32_bf16(vf0, pf1, o01, 0,0,0);
    o11 = __builtin_amdgcn_mfma_f32_16x16x32_bf16(vf1, pf1, o11, 0,0,0);
    o02 = __builtin_amdgcn_mfma_f32_16x16x32_bf16(vf0, pf2, o02, 0,0,0);
    o12 = __builtin_amdgcn_mfma_f32_16x16x32_bf16(vf1, pf2, o12, 0,0,0);
    // reload V for next phase (last use above)
    vf0 = *(const short8*)(vb + rk);
    vf1 = *(const short8*)(vb + (size_t)16*NTOK + rk);
  }

  // reduce lsum across quads (per query column cc)
  lsum0 += __shfl_xor(lsum0, 16, 64); lsum0 += __shfl_xor(lsum0, 32, 64);
  lsum1 += __shfl_xor(lsum1, 16, 64); lsum1 += __shfl_xor(lsum1, 32, 64);
  lsum2 += __shfl_xor(lsum2, 16, 64); lsum2 += __shfl_xor(lsum2, 32, 64);

  // ---- cross-wave merge (j = qq*8 + dh*4 + i) -----------------------------
  float* mg = mg_lds + w*1600;
  #pragma unroll
  for (int i=0;i<4;i++){
    mg[(0*8 + 0*4 + i)*64 + lane] = o00[i];
    mg[(0*8 + 1*4 + i)*64 + lane] = o10[i];
    mg[(1*8 + 0*4 + i)*64 + lane] = o01[i];
    mg[(1*8 + 1*4 + i)*64 + lane] = o11[i];
    mg[(2*8 + 0*4 + i)*64 + lane] = o02[i];
    mg[(2*8 + 1*4 + i)*64 + lane] = o12[i];
  }
  if (quad == 0){
    mg[1536 +  0 + cc] = lsum0;
    mg[1536 + 16 + cc] = lsum1;
    mg[1536 + 32 + cc] = lsum2;
  }
  __syncthreads();

  // waves 0..2 each finalize one q-fragment (wave 3 idles: 48q, 3 frags)
  if (w < 3){
    const float* m0 = mg_lds;
    const float* m1 = mg_lds + 1600;
    const float* m2 = mg_lds + 3200;
    const float* m3 = mg_lds + 4800;
    const int la = 1536 + w*16 + cc;
    float ls = (m0[la] + m1[la]) + (m2[la] + m3[la]);
    float inv = 1.f / ls;

    float r0, r1, r2, r3, r4, r5, r6, r7;
    {
      int a0 = (w*8 + 0)*64 + lane;
      r0 = (m0[a0] + m1[a0]) + (m2[a0] + m3[a0]);
      int a1 = (w*8 + 1)*64 + lane;
      r1 = (m0[a1] + m1[a1]) + (m2[a1] + m3[a1]);
      int a2 = (w*8 + 2)*64 + lane;
      r2 = (m0[a2] + m1[a2]) + (m2[a2] + m3[a2]);
      int a3 = (w*8 + 3)*64 + lane;
      r3 = (m0[a3] + m1[a3]) + (m2[a3] + m3[a3]);
      int a4 = (w*8 + 4)*64 + lane;
      r4 = (m0[a4] + m1[a4]) + (m2[a4] + m3[a4]);
      int a5 = (w*8 + 5)*64 + lane;
      r5 = (m0[a5] + m1[a5]) + (m2[a5] + m3[a5]);
      int a6 = (w*8 + 6)*64 + lane;
      r6 = (m0[a6] + m1[a6]) + (m2[a6] + m3[a6]);
      int a7 = (w*8 + 7)*64 + lane;
      r7 = (m0[a7] + m1[a7]) + (m2[a7] + m3[a7]);
    }

    const int qcol = q0 + w*16 + cc;
    unsigned short* dst = AO + (size_t)(b*2304 + qcol)*256 + h*32 + 4*quad;
    ushort4 p0;
    p0.x = f2bfu(r0*inv); p0.y = f2bfu(r1*inv);
    p0.z = f2bfu(r2*inv); p0.w = f2bfu(r3*inv);
    *(ushort4*)(dst) = p0;
    ushort4 p1;
    p1.x = f2bfu(r4*inv); p1.y = f2bfu(r5*inv);
    p1.z = f2bfu(r6*inv); p1.w = f2bfu(r7*inv);
    *(ushort4*)(dst + 16) = p1;
  }
}

// ---------------- BatchNorm finalize: pre fp32 chanmaj -> fp32 out ---------
__global__ __launch_bounds__(256) void bn_final_kernel(
    const float* __restrict__ pre, const float* __restrict__ bns,
    const float* __restrict__ g, const float* __restrict__ bt,
    float* __restrict__ out){
  int i0 = (blockIdx.x*256 + threadIdx.x)*4;
  int ch = (i0 / NTOK) & 255;
  float mean = bns[ch] * (1.f/9216.f);
  float var  = bns[256+ch] * (1.f/9216.f) - mean*mean;
  float scl = g[ch] * rsqrtf(fmaxf(var, 0.f) + 1e-5f);
  float sh  = bt[ch] - mean*scl;
  float4 x = *(const float4*)(pre + i0);
  *(float4*)(out + i0) = make_float4(x.x*scl+sh, x.y*scl+sh, x.z*scl+sh, x.w*scl+sh);
}

// ---------------- launch ----------------
extern "C" void kernel_launch(void* const* d_in, const int* in_sizes, int n_in,
                              void* d_out, int out_size, void* d_ws, size_t ws_size,
                              hipStream_t stream){
  const size_t NEED = 2112 + (size_t)15155200*2;     // 30.3 MB
  if (ws_size < NEED){
    trip_kernel<<<dim3((out_size+255)/256), dim3(256), 0, stream>>>((float*)d_out, out_size);
    return;
  }
  const float* q   = (const float*)d_in[0];
  const float* k   = (const float*)d_in[1];
  const float* v   = (const float*)d_in[2];
  const float* wq  = (const float*)d_in[3];
  const float* wk  = (const float*)d_in[4];
  const float* wv  = (const float*)d_in[5];
  const float* wfc = (const float*)d_in[6];
  const float* w1  = (const float*)d_in[7];
  const float* b1  = (const float*)d_in[8];
  const float* w2  = (const float*)d_in[9];
  const float* b2  = (const float*)d_in[10];
  const float* gm  = (const float*)d_in[11];
  const float* bt  = (const float*)d_in[12];

  float* ws  = (float*)d_ws;
  float* bns = ws;
  unsigned short* ub = (unsigned short*)(ws + 528);
  unsigned short* u_qT = ub;                 // -> AO
  unsigned short* u_kT = ub + 2654208;
  unsigned short* u_vT = ub + 5308416;
  unsigned short* u_Qt = ub + 7667712;
  unsigned short* u_Kt = ub + 10027008;      // -> pre (overlays Kt+V2)
  unsigned short* u_V2 = ub + 12386304;
  unsigned short* wqp  = ub + 14745600;
  unsigned short* wkp  = ub + 14819328;
  unsigned short* wvb  = ub + 14893056;
  unsigned short* wfcb = ub + 14958592;
  unsigned short* w1b  = ub + 15024128;
  unsigned short* w2b  = ub + 15089664;
  unsigned short* AO  = u_qT;
  float* pre = (float*)(u_Kt);

  setup_kernel<<<dim3(3400), dim3(256), 0, stream>>>(
      q, k, v, wq, wk, wv, wfc, w1, w2,
      u_qT, u_kT, u_vT, wqp, wkp, wvb, wfcb, w1b, w2b, bns);

  qkv_kernel<<<dim3(12,8,12), dim3(256), 0, stream>>>(u_qT, u_kT, u_vT, wqp, wkp, wvb, u_Qt, u_Kt, u_V2);

  attn_kernel<<<dim3(48,8,4), dim3(256), 0, stream>>>(u_Qt, u_Kt, u_V2, AO);

  ffn_kernel<<<dim3(144,4), dim3(256), 0, stream>>>(AO, wfcb, w1b, w2b, b1, b2, pre, bns);

  bn_final_kernel<<<dim3(2304), dim3(256), 0, stream>>>(pre, bns, gm, bt, (float*)d_out);
}

// Round 12
// 219.920 us; speedup vs baseline: 1.0074x; 1.0074x over previous
//
#include <hip/hip_runtime.h>
#include <hip/hip_bf16.h>

// Problem constants (B=4, FEAT=256, H=W=48, NH=8, DK=DV=32, PE=10)
// I/O: all inputs fp32, output fp32 (verified round 7/8).
// R8/R9 lesson: in-kernel grid sync costs 190-400us here; split bn_final wins.
// R12 theory: attn's 62us wall = L2 thrash (FETCH 41MB vs 15MB footprint;
// per-XCD working set 9.4MB > 4MB L2) -> HBM-latency-bound. Fix = XCD-group
// swizzle (footprint 1.18MB/XCD) + per-block key-phase rotation (concurrent
// same-group blocks read DIFFERENT lines -> no same-address convoy, which
// is what sank the R2/R3 swizzle-without-rotation).
#define NTOK 2304

typedef short  short8  __attribute__((ext_vector_type(8)));   // 8 bf16 MFMA frag
typedef unsigned short ushort8v __attribute__((ext_vector_type(8)));
typedef float  f32x4   __attribute__((ext_vector_type(4)));

static __device__ __forceinline__ unsigned short f2bfu(float f){
  __hip_bfloat16 h = __float2bfloat16(f);          // RNE
  union { __hip_bfloat16 h; unsigned short u; } cv; cv.h = h; return cv.u;
}

// ---- in-register P transpose helpers (no LDS round-trip) ------------------
static __device__ __forceinline__ void plane32(unsigned &a, unsigned &b){
  asm("v_permlane32_swap_b32 %0, %1" : "+v"(a), "+v"(b));
}
static __device__ __forceinline__ void plane16(unsigned &a, unsigned &b){
  asm("v_permlane16_swap_b32 %0, %1" : "+v"(a), "+v"(b));
}
// sa = scores keys 4q..4q+3, sb = keys 16+4q..16+4q+3 (query col cc) ->
// B-fragment short8 = P[keys 8q..8q+7][cc]. permlane32 (reg<->lane5) then
// permlane16 (reg<->lane4); verified vs MFMA C/D and A/B fragment maps.
static __device__ __forceinline__ short8 xpose_p(f32x4 sa, f32x4 sb){
  unsigned x0, x1, y0, y1;
  asm("v_cvt_pk_bf16_f32 %0, %1, %2" : "=v"(x0) : "v"(sa[0]), "v"(sa[1]));
  asm("v_cvt_pk_bf16_f32 %0, %1, %2" : "=v"(x1) : "v"(sa[2]), "v"(sa[3]));
  asm("v_cvt_pk_bf16_f32 %0, %1, %2" : "=v"(y0) : "v"(sb[0]), "v"(sb[1]));
  asm("v_cvt_pk_bf16_f32 %0, %1, %2" : "=v"(y1) : "v"(sb[2]), "v"(sb[3]));
  plane32(x0, y0);
  plane32(x1, y1);
  plane16(x0, y0);
  plane16(x1, y1);
  union { unsigned u[4]; short8 s; } r;
  r.u[0] = x0; r.u[1] = x1; r.u[2] = y0; r.u[3] = y1;
  return r.s;
}

// ---------------- workspace layout ----------------
// ws[0..512)   float bns: sum[256], sumsq[256]
// ws[512..528) spare
// ushort arena at ws+528 (offsets in ushorts):
//   qT   @ 0         2654208 (4*2304*288) -> AO (attn out, tokmaj 256-wide)
//   kT   @ 2654208   2654208
//   vT   @ 5308416   2359296
//   Qt   @ 7667712   2359296
//   Kt   @ 10027008  2359296  \__ pre (fp32 chanmaj) overlays Kt+V2 after attn
//   V2   @ 12386304  2359296  /
//   wqp  @ 14745600  73728   (pre-scaled by log2(e)/sqrt(dk))
//   wkp  @ 14819328  73728
//   wvb  @ 14893056  65536
//   wfcb @ 14958592  65536
//   w1b  @ 15024128  65536
//   w2b  @ 15089664  65536   (end 15155200)
// NEED = 2112 + 15155200*2 = 30,312,512 B

__global__ void trip_kernel(float* out, int n){
  int i = blockIdx.x*256 + threadIdx.x;
  if (i < n) out[i] = 1000.0f;   // sentinel: ws too small
}

// ---------------- fused setup: prep-transpose + PE + weight converts -------
__global__ __launch_bounds__(256) void setup_kernel(
    const float* __restrict__ q, const float* __restrict__ k,
    const float* __restrict__ v,
    const float* __restrict__ wq, const float* __restrict__ wk,
    const float* __restrict__ wv, const float* __restrict__ wfc,
    const float* __restrict__ w1, const float* __restrict__ w2,
    unsigned short* __restrict__ qT, unsigned short* __restrict__ kT,
    unsigned short* __restrict__ vT,
    unsigned short* __restrict__ wqp, unsigned short* __restrict__ wkp,
    unsigned short* __restrict__ wvb, unsigned short* __restrict__ wfcb,
    unsigned short* __restrict__ w1b, unsigned short* __restrict__ w2b,
    float* __restrict__ bns){
  const int bid = blockIdx.x;
  const int t = threadIdx.x;
  __shared__ __align__(16) unsigned short tile[64*72];

  if (bid < 1728){                       // ---- prep transpose ----
    if (bid == 0){ bns[t] = 0.f; bns[256+t] = 0.f; }
    const int x = bid % 36, rem = bid / 36;
    const int y = rem % 4, z = rem / 4;  // z 0..11
    const int tz = z >> 2, b = z & 3;
    const float* src = (tz==0) ? q : ((tz==1) ? k : v);
    unsigned short* dst = (tz==0) ? qT : ((tz==1) ? kT : vT);
    const int W = (tz==2) ? 256 : 288;
    const int n0 = x*64, c0 = y*64;
    const int jj = t & 7, cl = t >> 3;   // 8 n-chunks x 32 c-rows
    #pragma unroll
    for (int p=0; p<2; p++){
      int c = c0 + 32*p + cl;
      const float* s = src + (size_t)(b*256 + c)*NTOK + n0 + 8*jj;
      float4 f0 = *(const float4*)s;
      float4 f1 = *(const float4*)(s + 4);
      unsigned short* tr = tile + 32*p + cl;
      tr[(8*jj+0)*72] = f2bfu(f0.x); tr[(8*jj+1)*72] = f2bfu(f0.y);
      tr[(8*jj+2)*72] = f2bfu(f0.z); tr[(8*jj+3)*72] = f2bfu(f0.w);
      tr[(8*jj+4)*72] = f2bfu(f1.x); tr[(8*jj+5)*72] = f2bfu(f1.y);
      tr[(8*jj+6)*72] = f2bfu(f1.z); tr[(8*jj+7)*72] = f2bfu(f1.w);
    }
    __syncthreads();
    #pragma unroll
    for (int p=0; p<2; p++){
      int nl = 32*p + cl;
      ushort8v val = *(const ushort8v*)(tile + nl*72 + 8*jj);
      *(ushort8v*)(dst + (size_t)(b*2304 + n0 + nl)*W + c0 + 8*jj) = val;
    }
  } else if (bid < 1800){                // ---- pe_fill ----
    const int id2 = bid - 1728;
    const int x = id2 % 9, yy = id2 / 9;
    const int n = x*256 + t;             // 0..2303
    unsigned short* buf = (yy < 4) ? qT : kT;
    const int b = yy & 3;
    const int i = n / 48, j = n - 48*i;
    const float k2pi = 6.283185307179586f;
    const float f = k2pi / 48.000001f;
    float ey = (float)(i+1) * f;
    float ex = (float)(j+1) * f;
    unsigned short u[32];
    #pragma unroll
    for (int p=0; p<10; p++){
      float inv = exp2f(-2.6575424759098898f * (float)(p >> 1));
      float vy = ey*inv, vx = ex*inv, vo = k2pi*inv;
      u[p]    = f2bfu((p&1) ? cosf(vy) : sinf(vy));
      u[10+p] = f2bfu((p&1) ? cosf(vx) : sinf(vx));
      u[20+p] = f2bfu((p&1) ? cosf(vo) : sinf(vo));
    }
    u[30] = 0; u[31] = 0;
    unsigned short* dst = buf + (size_t)(b*2304 + n)*288 + 256;
    #pragma unroll
    for (int m=0; m<4; m++) *(ushort8v*)(dst + 8*m) = *(const ushort8v*)(u + 8*m);
  } else if (bid < 2376){                // ---- padw ----
    const int id3 = bid - 1800;
    const int x = id3 % 288, y = id3 / 288;
    const int idx = x*256 + t;           // 0..73727
    const float* src = y ? wk : wq;
    unsigned short* dst = y ? wkp : wqp;
    // wq scale = log2(e)/sqrt(32): scores feed exp2 directly (exp2(s*log2e)=e^s)
    const float scale = y ? 1.f : 0.25503486f;
    int row = idx / 288, col = idx - row*288;
    dst[idx] = (col < 286) ? f2bfu(src[row*286 + col] * scale) : (unsigned short)0;
  } else {                               // ---- convw ----
    const int id4 = bid - 2376;
    const int x = id4 % 256, y = id4 / 256;
    const int idx = x*256 + t;           // 0..65535
    const float* src = (y==0)?wv:((y==1)?wfc:((y==2)?w1:w2));
    unsigned short* dst = (y==0)?wvb:((y==1)?wfcb:((y==2)?w1b:w2b));
    dst[idx] = f2bfu(src[idx]);
  }
}

// ---------------- GEMM cores -----------------------------------------------
// 3-token-fragment core: wave computes 48 tok x 32 oc (B-fragment reuse x3)
template<int KSTEPS>
static __device__ __forceinline__ void gemm3_core(
    const unsigned short* __restrict__ a0,
    const unsigned short* __restrict__ a1,
    const unsigned short* __restrict__ a2,
    const unsigned short* __restrict__ wrow, int wstride, f32x4 acc[3][2]){
  #pragma unroll
  for (int kk=0; kk<KSTEPS; kk++){
    short8 af0 = *(const short8*)(a0 + 32*kk);
    short8 af1 = *(const short8*)(a1 + 32*kk);
    short8 af2 = *(const short8*)(a2 + 32*kk);
    #pragma unroll
    for (int to=0; to<2; to++){
      short8 bf = *(const short8*)(wrow + (size_t)(16*to)*wstride + 32*kk);
      acc[0][to] = __builtin_amdgcn_mfma_f32_16x16x32_bf16(af0, bf, acc[0][to], 0,0,0);
      acc[1][to] = __builtin_amdgcn_mfma_f32_16x16x32_bf16(af1, bf, acc[1][to], 0,0,0);
      acc[2][to] = __builtin_amdgcn_mfma_f32_16x16x32_bf16(af2, bf, acc[2][to], 0,0,0);
    }
  }
}

// epilogue: token-major bf16 (wave-private LDS transpose; 16 tok x 32 oc)
static __device__ __forceinline__ void epi_tok(
    const f32x4* acc, unsigned short* __restrict__ out_tok,
    int b, int tok, int n0, int lane, int quad, int cc,
    unsigned short* __restrict__ tlw){
  #pragma unroll
  for (int to=0; to<2; to++)
    #pragma unroll
    for (int r=0; r<4; r++)
      tlw[(4*quad + r)*40 + 16*to + cc] = f2bfu(acc[to][r]);
  const int row = lane & 15, ch = lane >> 4;
  ushort8v val = *(const ushort8v*)(tlw + row*40 + 8*ch);
  *(ushort8v*)(out_tok + (size_t)(b*2304 + tok + row)*256 + n0 + 8*ch) = val;
}

// epilogue: channel-major bf16
static __device__ __forceinline__ void epi_chan(
    const f32x4* acc, unsigned short* __restrict__ out_chan,
    int b, int tok, int n0, int quad, int cc){
  #pragma unroll
  for (int to=0; to<2; to++){
    ushort4 pk;
    pk.x = f2bfu(acc[to][0]); pk.y = f2bfu(acc[to][1]);
    pk.z = f2bfu(acc[to][2]); pk.w = f2bfu(acc[to][3]);
    *(ushort4*)(out_chan + (size_t)(b*256 + n0 + 16*to + cc)*NTOK + tok + 4*quad) = pk;
  }
}

// ---------------- fused QKV projections ------------------------------------
// grid (12, 8, 12): x -> 192 tok (48/wave, 3 fragments), y -> 32 oc,
// z: tz = z>>2 (0=Q,1=K,2=V), b=z&3. 1152 blocks, single dispatch round.
__global__ __launch_bounds__(256) void qkv_kernel(
    const unsigned short* __restrict__ qT, const unsigned short* __restrict__ kT,
    const unsigned short* __restrict__ vT,
    const unsigned short* __restrict__ wqp, const unsigned short* __restrict__ wkp,
    const unsigned short* __restrict__ wvb,
    unsigned short* __restrict__ Qt, unsigned short* __restrict__ Kt,
    unsigned short* __restrict__ V2){
  const int t = threadIdx.x;
  const int w = t >> 6, lane = t & 63;
  const int quad = lane >> 4, cc = lane & 15;
  const int t0 = blockIdx.x*192, n0 = blockIdx.y*32;
  const int tz = blockIdx.z >> 2, b = blockIdx.z & 3;
  const int tok = t0 + 48*w;
  __shared__ __align__(16) unsigned short tl[4*16*40];
  unsigned short* tlw = tl + w*640;

  f32x4 acc[3][2];
  #pragma unroll
  for (int f=0; f<3; f++){
    acc[f][0] = (f32x4){0.f,0.f,0.f,0.f};
    acc[f][1] = acc[f][0];
  }

  if (tz == 0){
    const unsigned short* a0 = qT + (size_t)(b*2304 + tok + cc)*288 + 8*quad;
    gemm3_core<9>(a0, a0 + (size_t)16*288, a0 + (size_t)32*288,
                  wqp + (size_t)(n0 + cc)*288 + 8*quad, 288, acc);
    epi_tok(acc[0], Qt, b, tok,      n0, lane, quad, cc, tlw);
    epi_tok(acc[1], Qt, b, tok + 16, n0, lane, quad, cc, tlw);
    epi_tok(acc[2], Qt, b, tok + 32, n0, lane, quad, cc, tlw);
  } else if (tz == 1){
    const unsigned short* a0 = kT + (size_t)(b*2304 + tok + cc)*288 + 8*quad;
    gemm3_core<9>(a0, a0 + (size_t)16*288, a0 + (size_t)32*288,
                  wkp + (size_t)(n0 + cc)*288 + 8*quad, 288, acc);
    epi_tok(acc[0], Kt, b, tok,      n0, lane, quad, cc, tlw);
    epi_tok(acc[1], Kt, b, tok + 16, n0, lane, quad, cc, tlw);
    epi_tok(acc[2], Kt, b, tok + 32, n0, lane, quad, cc, tlw);
  } else {
    const unsigned short* a0 = vT + (size_t)(b*2304 + tok + cc)*256 + 8*quad;
    gemm3_core<8>(a0, a0 + (size_t)16*256, a0 + (size_t)32*256,
                  wvb + (size_t)(n0 + cc)*256 + 8*quad, 256, acc);
    epi_chan(acc[0], V2, b, tok,      n0, quad, cc);
    epi_chan(acc[1], V2, b, tok + 16, n0, quad, cc);
    epi_chan(acc[2], V2, b, tok + 32, n0, quad, cc);
  }
}

// ---------------- fused FFN: fc -> ffn1(relu) -> ffn2 + resid + BN stats ---
// grid (144, 4), block 256 = 4 waves. Block owns 16 tokens x all 256 oc;
// intermediates in LDS [16][264] bf16; residual (fc out) in registers fp32.
__global__ __launch_bounds__(256) void ffn_kernel(
    const unsigned short* __restrict__ AO,
    const unsigned short* __restrict__ wfcb,
    const unsigned short* __restrict__ w1b,
    const unsigned short* __restrict__ w2b,
    const float* __restrict__ b1, const float* __restrict__ b2,
    float* __restrict__ pre_out, float* __restrict__ bns){
  const int t = threadIdx.x;
  const int w = t >> 6, lane = t & 63;
  const int quad = lane >> 4, cc = lane & 15;
  const int tok0 = blockIdx.x * 16;
  const int b = blockIdx.y;
  const int ocb = 64 * w;

  __shared__ __align__(16) unsigned short T0[16*264];   // Ofc (bf16 tokmaj)
  __shared__ __align__(16) unsigned short T1[16*264];   // h1

  // ---- GEMM1: Ofc = AO x wfc^T (K=256); acc1 kept live as fp32 residual --
  const unsigned short* arow = AO + (size_t)(b*2304 + tok0 + cc)*256 + 8*quad;
  f32x4 acc1[4];
  acc1[0] = (f32x4){0.f,0.f,0.f,0.f}; acc1[1]=acc1[0]; acc1[2]=acc1[0]; acc1[3]=acc1[0];
  #pragma unroll
  for (int kk=0; kk<8; kk++){
    short8 af = *(const short8*)(arow + 32*kk);
    #pragma unroll
    for (int of=0; of<4; of++){
      short8 bf = *(const short8*)(wfcb + (size_t)(ocb + 16*of + cc)*256 + 8*quad + 32*kk);
      acc1[of] = __builtin_amdgcn_mfma_f32_16x16x32_bf16(af, bf, acc1[of], 0,0,0);
    }
  }
  #pragma unroll
  for (int of=0; of<4; of++)
    #pragma unroll
    for (int r=0; r<4; r++)
      T0[(4*quad + r)*264 + ocb + 16*of + cc] = f2bfu(acc1[of][r]);
  __syncthreads();

  // ---- GEMM2: h1 = relu(Ofc x w1^T + b1) ---------------------------------
  f32x4 acc2[4];
  acc2[0] = (f32x4){0.f,0.f,0.f,0.f}; acc2[1]=acc2[0]; acc2[2]=acc2[0]; acc2[3]=acc2[0];
  #pragma unroll
  for (int kk=0; kk<8; kk++){
    short8 af = *(const short8*)(T0 + cc*264 + 8*quad + 32*kk);
    #pragma unroll
    for (int of=0; of<4; of++){
      short8 bf = *(const short8*)(w1b + (size_t)(ocb + 16*of + cc)*256 + 8*quad + 32*kk);
      acc2[of] = __builtin_amdgcn_mfma_f32_16x16x32_bf16(af, bf, acc2[of], 0,0,0);
    }
  }
  #pragma unroll
  for (int of=0; of<4; of++){
    float bv = b1[ocb + 16*of + cc];
    #pragma unroll
    for (int r=0; r<4; r++){
      float hv = fmaxf(acc2[of][r] + bv, 0.f);
      T1[(4*quad + r)*264 + ocb + 16*of + cc] = f2bfu(hv);
    }
  }
  __syncthreads();

  // ---- GEMM3: h2 = h1 x w2^T + b2; pre = h2 + Ofc(fp32); BN stats --------
  f32x4 acc3[4];
  acc3[0] = (f32x4){0.f,0.f,0.f,0.f}; acc3[1]=acc3[0]; acc3[2]=acc3[0]; acc3[3]=acc3[0];
  #pragma unroll
  for (int kk=0; kk<8; kk++){
    short8 af = *(const short8*)(T1 + cc*264 + 8*quad + 32*kk);
    #pragma unroll
    for (int of=0; of<4; of++){
      short8 bf = *(const short8*)(w2b + (size_t)(ocb + 16*of + cc)*256 + 8*quad + 32*kk);
      acc3[of] = __builtin_amdgcn_mfma_f32_16x16x32_bf16(af, bf, acc3[of], 0,0,0);
    }
  }
  #pragma unroll
  for (int of=0; of<4; of++){
    const int oc = ocb + 16*of + cc;
    float bv = b2[oc];
    float p0 = acc3[of][0] + bv + acc1[of][0];
    float p1 = acc3[of][1] + bv + acc1[of][1];
    float p2 = acc3[of][2] + bv + acc1[of][2];
    float p3 = acc3[of][3] + bv + acc1[of][3];
    *(float4*)(pre_out + (size_t)(b*256 + oc)*NTOK + tok0 + 4*quad) =
        make_float4(p0, p1, p2, p3);
    float s1 = (p0+p1)+(p2+p3);
    float s2 = (p0*p0+p1*p1)+(p2*p2+p3*p3);
    s1 += __shfl_xor(s1, 16, 64); s1 += __shfl_xor(s1, 32, 64);
    s2 += __shfl_xor(s2, 16, 64); s2 += __shfl_xor(s2, 32, 64);
    if (quad == 0){
      atomicAdd(&bns[oc],       s1);
      atomicAdd(&bns[256 + oc], s2);
    }
  }
}

// ---------------- attention: 48q blocks, XCD-local K/V + phase rotation ----
// grid (1536), block 256 = 4 waves. flat = 8*ii + xcd; each XCD owns 4
// complete (b,h) groups (192 blocks) -> per-XCD K/V footprint 4 x 295KB =
// 1.18MB << 4MB L2 (kills the thrash: R11 FETCH 41MB vs 15MB ideal).
// Each block rotates its key-walk start phase by qblk%18 so concurrent
// same-group blocks read DIFFERENT lines (kills the same-address convoy
// that sank R2/R3's rotation-less swizzle). No-max softmax -> key order
// commutative. Wave: 3 q-fragments x 576-key slice, 18 circular phases,
// distance-1 reload-after-use prefetch.
__global__ __launch_bounds__(256) void attn_kernel(
    const unsigned short* __restrict__ Qt, const unsigned short* __restrict__ Kt,
    const unsigned short* __restrict__ V2, unsigned short* __restrict__ AO){
  const int t = threadIdx.x;
  const int w = t >> 6, lane = t & 63;
  const int quad = lane >> 4, cc = lane & 15;

  // bijective XCD remap over 1536 = 8 xcd * (4 groups * 48 qblk)
  const int flat = blockIdx.x;
  const int xcd = flat & 7;
  const int ii  = flat >> 3;            // 0..191
  const int sub = ii / 48;              // 0..3
  const int g   = xcd*4 + sub;          // 0..31
  const int qblk = ii - sub*48;         // 0..47
  const int b = g >> 3, h = g & 7;
  const int q0 = qblk*48;
  const int ph = qblk % 18;             // key-phase rotation

  const unsigned short* qb = Qt + (size_t)(b*2304 + q0 + cc)*256 + h*32 + 8*quad;
  short8 qf0 = *(const short8*)(qb);
  short8 qf1 = *(const short8*)(qb + 16*256);
  short8 qf2 = *(const short8*)(qb + 32*256);

  const unsigned short* kb = Kt + (size_t)(b*2304 + cc)*256 + h*32 + 8*quad;
  const unsigned short* vb = V2 + (size_t)(b*256 + h*32 + cc)*NTOK + 8*quad;

  // merge: 4 regions x 1600 floats (24 j-slots x 64 lanes + 48 lsum + pad)
  __shared__ __align__(16) float mg_lds[4*1600];

  f32x4 o00={0.f,0.f,0.f,0.f}, o10=o00, o01=o00, o11=o00, o02=o00, o12=o00;
  float lsum0=0.f, lsum1=0.f, lsum2=0.f;

  const int kstart = w*576;
  int kc = ph;                          // current phase 0..17
  {
    const int k0 = kstart + kc*32;
    // prologue loads at rotated start phase
    // (declared below as kf/vf registers)
  }
  short8 kf0 = *(const short8*)(kb + (size_t)(kstart + kc*32)*256);
  short8 kf1 = *(const short8*)(kb + (size_t)(kstart + kc*32 + 16)*256);
  short8 vf0 = *(const short8*)(vb + kstart + kc*32);
  short8 vf1 = *(const short8*)(vb + (size_t)16*NTOK + kstart + kc*32);

  #pragma unroll 1
  for (int it = 0; it < 18; ++it){
    int kn = kc + 1; if (kn == 18) kn = 0;        // next phase (circular)
    const int rk = kstart + kn*32;
    const f32x4 z = {0.f,0.f,0.f,0.f};

    // QK: 6 MFMA over 3 query fragments
    f32x4 s00 = __builtin_amdgcn_mfma_f32_16x16x32_bf16(kf0, qf0, z, 0,0,0);
    f32x4 s10 = __builtin_amdgcn_mfma_f32_16x16x32_bf16(kf1, qf0, z, 0,0,0);
    f32x4 s01 = __builtin_amdgcn_mfma_f32_16x16x32_bf16(kf0, qf1, z, 0,0,0);
    f32x4 s11 = __builtin_amdgcn_mfma_f32_16x16x32_bf16(kf1, qf1, z, 0,0,0);
    f32x4 s02 = __builtin_amdgcn_mfma_f32_16x16x32_bf16(kf0, qf2, z, 0,0,0);
    f32x4 s12 = __builtin_amdgcn_mfma_f32_16x16x32_bf16(kf1, qf2, z, 0,0,0);
    // reload K for next phase (last use above)
    kf0 = *(const short8*)(kb + (size_t)rk*256);
    kf1 = *(const short8*)(kb + (size_t)(rk+16)*256);

    // softmax numerator + per-qq chains (independent -> ILP)
    #pragma unroll
    for (int r=0; r<4; r++){
      s00[r] = __builtin_amdgcn_exp2f(s00[r]);
      s10[r] = __builtin_amdgcn_exp2f(s10[r]);
      s01[r] = __builtin_amdgcn_exp2f(s01[r]);
      s11[r] = __builtin_amdgcn_exp2f(s11[r]);
      s02[r] = __builtin_amdgcn_exp2f(s02[r]);
      s12[r] = __builtin_amdgcn_exp2f(s12[r]);
    }
    lsum0 += ((s00[0]+s00[1])+(s00[2]+s00[3])) + ((s10[0]+s10[1])+(s10[2]+s10[3]));
    lsum1 += ((s01[0]+s01[1])+(s01[2]+s01[3])) + ((s11[0]+s11[1])+(s11[2]+s11[3]));
    lsum2 += ((s02[0]+s02[1])+(s02[2]+s02[3])) + ((s12[0]+s12[1])+(s12[2]+s12[3]));

    short8 pf0 = xpose_p(s00, s10);
    short8 pf1 = xpose_p(s01, s11);
    short8 pf2 = xpose_p(s02, s12);

    o00 = __builtin_amdgcn_mfma_f32_16x16x32_bf16(vf0, pf0, o00, 0,0,0);
    o10 = __builtin_amdgcn_mfma_f32_16x16x32_bf16(vf1, pf0, o10, 0,0,0);
    o01 = __builtin_amdgcn_mfma_f32_16x16x32_bf16(vf0, pf1, o01, 0,0,0);
    o11 = __builtin_amdgcn_mfma_f32_16x16x32_bf16(vf1, pf1, o11, 0,0,0);
    o02 = __builtin_amdgcn_mfma_f32_16x16x32_bf16(vf0, pf2, o02, 0,0,0);
    o12 = __builtin_amdgcn_mfma_f32_16x16x32_bf16(vf1, pf2, o12, 0,0,0);
    // reload V for next phase (last use above)
    vf0 = *(const short8*)(vb + rk);
    vf1 = *(const short8*)(vb + (size_t)16*NTOK + rk);

    kc = kn;
  }

  // reduce lsum across quads (per query column cc)
  lsum0 += __shfl_xor(lsum0, 16, 64); lsum0 += __shfl_xor(lsum0, 32, 64);
  lsum1 += __shfl_xor(lsum1, 16, 64); lsum1 += __shfl_xor(lsum1, 32, 64);
  lsum2 += __shfl_xor(lsum2, 16, 64); lsum2 += __shfl_xor(lsum2, 32, 64);

  // ---- cross-wave merge (j = qq*8 + dh*4 + i) -----------------------------
  float* mg = mg_lds + w*1600;
  #pragma unroll
  for (int i=0;i<4;i++){
    mg[(0*8 + 0*4 + i)*64 + lane] = o00[i];
    mg[(0*8 + 1*4 + i)*64 + lane] = o10[i];
    mg[(1*8 + 0*4 + i)*64 + lane] = o01[i];
    mg[(1*8 + 1*4 + i)*64 + lane] = o11[i];
    mg[(2*8 + 0*4 + i)*64 + lane] = o02[i];
    mg[(2*8 + 1*4 + i)*64 + lane] = o12[i];
  }
  if (quad == 0){
    mg[1536 +  0 + cc] = lsum0;
    mg[1536 + 16 + cc] = lsum1;
    mg[1536 + 32 + cc] = lsum2;
  }
  __syncthreads();

  // waves 0..2 each finalize one q-fragment (wave 3 idles: 48q, 3 frags)
  if (w < 3){
    const float* m0 = mg_lds;
    const float* m1 = mg_lds + 1600;
    const float* m2 = mg_lds + 3200;
    const float* m3 = mg_lds + 4800;
    const int la = 1536 + w*16 + cc;
    float ls = (m0[la] + m1[la]) + (m2[la] + m3[la]);
    float inv = 1.f / ls;

    float r0, r1, r2, r3, r4, r5, r6, r7;
    {
      int a0 = (w*8 + 0)*64 + lane;
      r0 = (m0[a0] + m1[a0]) + (m2[a0] + m3[a0]);
      int a1 = (w*8 + 1)*64 + lane;
      r1 = (m0[a1] + m1[a1]) + (m2[a1] + m3[a1]);
      int a2 = (w*8 + 2)*64 + lane;
      r2 = (m0[a2] + m1[a2]) + (m2[a2] + m3[a2]);
      int a3 = (w*8 + 3)*64 + lane;
      r3 = (m0[a3] + m1[a3]) + (m2[a3] + m3[a3]);
      int a4 = (w*8 + 4)*64 + lane;
      r4 = (m0[a4] + m1[a4]) + (m2[a4] + m3[a4]);
      int a5 = (w*8 + 5)*64 + lane;
      r5 = (m0[a5] + m1[a5]) + (m2[a5] + m3[a5]);
      int a6 = (w*8 + 6)*64 + lane;
      r6 = (m0[a6] + m1[a6]) + (m2[a6] + m3[a6]);
      int a7 = (w*8 + 7)*64 + lane;
      r7 = (m0[a7] + m1[a7]) + (m2[a7] + m3[a7]);
    }

    const int qcol = q0 + w*16 + cc;
    unsigned short* dst = AO + (size_t)(b*2304 + qcol)*256 + h*32 + 4*quad;
    ushort4 p0;
    p0.x = f2bfu(r0*inv); p0.y = f2bfu(r1*inv);
    p0.z = f2bfu(r2*inv); p0.w = f2bfu(r3*inv);
    *(ushort4*)(dst) = p0;
    ushort4 p1;
    p1.x = f2bfu(r4*inv); p1.y = f2bfu(r5*inv);
    p1.z = f2bfu(r6*inv); p1.w = f2bfu(r7*inv);
    *(ushort4*)(dst + 16) = p1;
  }
}

// ---------------- BatchNorm finalize: pre fp32 chanmaj -> fp32 out ---------
__global__ __launch_bounds__(256) void bn_final_kernel(
    const float* __restrict__ pre, const float* __restrict__ bns,
    const float* __restrict__ g, const float* __restrict__ bt,
    float* __restrict__ out){
  int i0 = (blockIdx.x*256 + threadIdx.x)*4;
  int ch = (i0 / NTOK) & 255;
  float mean = bns[ch] * (1.f/9216.f);
  float var  = bns[256+ch] * (1.f/9216.f) - mean*mean;
  float scl = g[ch] * rsqrtf(fmaxf(var, 0.f) + 1e-5f);
  float sh  = bt[ch] - mean*scl;
  float4 x = *(const float4*)(pre + i0);
  *(float4*)(out + i0) = make_float4(x.x*scl+sh, x.y*scl+sh, x.z*scl+sh, x.w*scl+sh);
}

// ---------------- launch ----------------
extern "C" void kernel_launch(void* const* d_in, const int* in_sizes, int n_in,
                              void* d_out, int out_size, void* d_ws, size_t ws_size,
                              hipStream_t stream){
  const size_t NEED = 2112 + (size_t)15155200*2;     // 30.3 MB
  if (ws_size < NEED){
    trip_kernel<<<dim3((out_size+255)/256), dim3(256), 0, stream>>>((float*)d_out, out_size);
    return;
  }
  const float* q   = (const float*)d_in[0];
  const float* k   = (const float*)d_in[1];
  const float* v   = (const float*)d_in[2];
  const float* wq  = (const float*)d_in[3];
  const float* wk  = (const float*)d_in[4];
  const float* wv  = (const float*)d_in[5];
  const float* wfc = (const float*)d_in[6];
  const float* w1  = (const float*)d_in[7];
  const float* b1  = (const float*)d_in[8];
  const float* w2  = (const float*)d_in[9];
  const float* b2  = (const float*)d_in[10];
  const float* gm  = (const float*)d_in[11];
  const float* bt  = (const float*)d_in[12];

  float* ws  = (float*)d_ws;
  float* bns = ws;
  unsigned short* ub = (unsigned short*)(ws + 528);
  unsigned short* u_qT = ub;                 // -> AO
  unsigned short* u_kT = ub + 2654208;
  unsigned short* u_vT = ub + 5308416;
  unsigned short* u_Qt = ub + 7667712;
  unsigned short* u_Kt = ub + 10027008;      // -> pre (overlays Kt+V2)
  unsigned short* u_V2 = ub + 12386304;
  unsigned short* wqp  = ub + 14745600;
  unsigned short* wkp  = ub + 14819328;
  unsigned short* wvb  = ub + 14893056;
  unsigned short* wfcb = ub + 14958592;
  unsigned short* w1b  = ub + 15024128;
  unsigned short* w2b  = ub + 15089664;
  unsigned short* AO  = u_qT;
  float* pre = (float*)(u_Kt);

  setup_kernel<<<dim3(3400), dim3(256), 0, stream>>>(
      q, k, v, wq, wk, wv, wfc, w1, w2,
      u_qT, u_kT, u_vT, wqp, wkp, wvb, wfcb, w1b, w2b, bns);

  qkv_kernel<<<dim3(12,8,12), dim3(256), 0, stream>>>(u_qT, u_kT, u_vT, wqp, wkp, wvb, u_Qt, u_Kt, u_V2);

  attn_kernel<<<dim3(1536), dim3(256), 0, stream>>>(u_Qt, u_Kt, u_V2, AO);

  ffn_kernel<<<dim3(144,4), dim3(256), 0, stream>>>(AO, wfcb, w1b, w2b, b1, b2, pre, bns);

  bn_final_kernel<<<dim3(2304), dim3(256), 0, stream>>>(pre, bns, gm, bt, (float*)d_out);
}